// Round 23
// baseline (484.637 us; speedup 1.0000x reference)
//
#include <hip/hip_runtime.h>

#define B_ 4
#define T_ 4096
#define E_ 512
#define A_ 64
#define SQSCALE 0.1803368801111204f   // log2(e)/8 : folds softmax scale + exp->exp2

typedef __attribute__((ext_vector_type(8)))  short bf16x8;
typedef __attribute__((ext_vector_type(8)))  unsigned short ushort8;
typedef __attribute__((ext_vector_type(4)))  unsigned int   u32x4;
typedef __attribute__((ext_vector_type(4)))  float f32x4;
typedef __attribute__((ext_vector_type(16))) float f32x16;

__device__ __forceinline__ unsigned short f2bf(float x) {
    union { float f; unsigned int u; } v; v.f = x;
    unsigned int r = v.u + 0x7fffu + ((v.u >> 16) & 1u);
    return (unsigned short)(r >> 16);
}
__device__ __forceinline__ unsigned cvtpk(float a, float b) {
    unsigned r;
    asm("v_cvt_pk_bf16_f32 %0, %1, %2" : "=v"(r) : "v"(a), "v"(b));
    return r;
}
__device__ __forceinline__ void pls(unsigned &a, unsigned &b) {
    asm("v_permlane32_swap_b32 %0, %1" : "+v"(a), "+v"(b));
}

// ---- Kernel 0: W -> Wp, fragment-packed bf16 B-frags [nt 12][ks 16][lane 64]x8
__global__ __launch_bounds__(256) void prep_w(
    const float* __restrict__ Wq, const float* __restrict__ Wk,
    const float* __restrict__ Wv, unsigned short* __restrict__ Wp)
{
    const int e = blockIdx.x * 256 + threadIdx.x;
    const int ks = (e >> 6) & 15;
    const int nt = e >> 10;
    const int l  = e & 63;
    const int col = nt * 16 + (l & 15);
    const int kb  = ks * 32 + (l >> 4) * 8;
    const float* W = (col < 64) ? Wq : ((col < 128) ? Wk : Wv);
    const int cc = col & 63;
    const float sc = (col < 64) ? SQSCALE : 1.f;
    union { unsigned short s[8]; ushort8 v; } u;
    #pragma unroll
    for (int j = 0; j < 8; ++j) u.s[j] = f2bf(W[(kb + j) * 64 + cc] * sc);
    *(ushort8*)&Wp[(size_t)e * 8] = u.v;
}

// ---- Kernel 1: QKV projection via bf16 MFMA (R17 version, byte-identical) --
__global__ __launch_bounds__(768, 4) void qkv_proj_kernel(
    const float* __restrict__ emb, const unsigned short* __restrict__ Wp,
    unsigned short* __restrict__ Qp, unsigned short* __restrict__ Kp,
    unsigned short* __restrict__ Vp)
{
    __shared__ unsigned short at[32][536];
    __shared__ unsigned short qt[32][72];
    __shared__ unsigned short kt[32][72];
    __shared__ unsigned short vt[64][40];
    const int tid = threadIdx.x;
    const long row0 = (long)blockIdx.x * 32;

    if (tid < 512) {
        const int r = tid >> 4, c16 = tid & 15;
        const float* __restrict__ src = emb + (row0 + r) * 512;
        #pragma unroll
        for (int j = 0; j < 4; ++j) {
            const int col = j * 128 + c16 * 8;
            const float4 x0 = *(const float4*)(src + col);
            const float4 x1 = *(const float4*)(src + col + 4);
            u32x4 p;
            p[0] = cvtpk(x0.x, x0.y); p[1] = cvtpk(x0.z, x0.w);
            p[2] = cvtpk(x1.x, x1.y); p[3] = cvtpk(x1.z, x1.w);
            *(u32x4*)&at[r][col] = p;
        }
    }
    __syncthreads();

    const int w = tid >> 6, lane = tid & 63;
    const int c = lane & 15, hi = lane >> 4;

    f32x4 acc[2];
    acc[0] = (f32x4){0.f, 0.f, 0.f, 0.f};
    acc[1] = (f32x4){0.f, 0.f, 0.f, 0.f};

    #pragma unroll
    for (int ks = 0; ks < 16; ++ks) {
        const bf16x8 bf_ = *(const bf16x8*)&Wp[((size_t)(w * 16 + ks) * 64 + lane) * 8];
        const bf16x8 a0 = *(const bf16x8*)&at[c][ks * 32 + hi * 8];
        const bf16x8 a1 = *(const bf16x8*)&at[16 + c][ks * 32 + hi * 8];
        acc[0] = __builtin_amdgcn_mfma_f32_16x16x32_bf16(a0, bf_, acc[0], 0, 0, 0);
        acc[1] = __builtin_amdgcn_mfma_f32_16x16x32_bf16(a1, bf_, acc[1], 0, 0, 0);
    }

    #pragma unroll
    for (int rr = 0; rr < 2; ++rr)
        #pragma unroll
        for (int r4 = 0; r4 < 4; ++r4) {
            const int rloc = rr * 16 + hi * 4 + r4;
            const unsigned short v = f2bf(acc[rr][r4]);
            if (w < 4)       qt[rloc][w * 16 + c] = v;
            else if (w < 8)  kt[rloc][(w - 4) * 16 + c] = v;
            else             vt[(w - 8) * 16 + c][rloc] = v;
        }
    __syncthreads();

    const int tloc = (int)(row0 & 4095);
    const long bb = row0 >> 12;
    const int ci  = tloc >> 6;
    const int f_  = (tloc >> 5) & 1;
    const int ks0 = (tloc >> 4) & 3;
    const int tt  = tloc >> 5;
    if (tid < 256) {
        const int kk = tid >> 6, l = tid & 63;
        const ushort8 kval = *(const ushort8*)&kt[l & 31][kk * 16 + (l >> 5) * 8];
        *(ushort8*)&Kp[((((bb * 64 + ci) * 2 + f_) * 4 + kk) * 64 + l) * 8] = kval;
        const ushort8 qval = *(const ushort8*)&qt[l & 31][kk * 16 + (l >> 5) * 8];
        *(ushort8*)&Qp[(((bb * 128 + tt) * 4 + kk) * 64 + l) * 8] = qval;
    } else if (tid < 512) {
        const int e = tid - 256;
        const int ksl = e >> 7, ct = (e >> 6) & 1, l = e & 63;
        const ushort8 val = *(const ushort8*)&vt[ct * 32 + (l & 31)][ksl * 16 + (l >> 5) * 8];
        *(ushort8*)&Vp[((((bb * 64 + ci) * 4 + ks0 + ksl) * 2 + ct) * 64 + l) * 8] = val;
    }
}

// ---- shared tile structs (real attn; R22 byte-identical) -------------------
struct TS {
    bf16x8 qf[4];
    f32x16 acc[2];
    float m, l;
    int qb;
};

__device__ __forceinline__ void tile_init(TS& s, int t,
    const unsigned short* __restrict__ Qpb, int lane)
{
    s.qb = t << 5;
    #pragma unroll
    for (int kk = 0; kk < 4; ++kk)
        s.qf[kk] = *(const bf16x8*)&Qpb[(((size_t)t * 4 + kk) * 64 + lane) * 8];
    #pragma unroll
    for (int ct = 0; ct < 2; ++ct)
        #pragma unroll
        for (int j = 0; j < 16; ++j) s.acc[ct][j] = 0.f;
    s.m = -1e30f; s.l = 0.f;
}

__device__ __forceinline__ void tile_compute(TS& s, const bf16x8 kf[2][4],
    const bf16x8 vf[4][2], int s0, int h, int c)
{
    f32x16 sf[2];
    #pragma unroll
    for (int f = 0; f < 2; ++f)
        #pragma unroll
        for (int j = 0; j < 16; ++j) sf[f][j] = 0.f;
    __builtin_amdgcn_s_setprio(1);
    #pragma unroll
    for (int f = 0; f < 2; ++f)
        #pragma unroll
        for (int kk = 0; kk < 4; ++kk)
            sf[f] = __builtin_amdgcn_mfma_f32_32x32x16_bf16(kf[f][kk], s.qf[kk], sf[f], 0, 0, 0);
    __builtin_amdgcn_s_setprio(0);

    if (s0 + 63 > s.qb) {
        #pragma unroll
        for (int f = 0; f < 2; ++f)
            #pragma unroll
            for (int r = 0; r < 16; ++r) {
                const int key = s0 + f * 32 + ((r & 3) + 8 * (r >> 2)) + 4 * h;
                if (key > s.qb + c) sf[f][r] = -1e30f;
            }
    }

    float t0 = fmaxf(sf[0][0], sf[1][0]);
    float t1 = fmaxf(sf[0][1], sf[1][1]);
    float t2 = fmaxf(sf[0][2], sf[1][2]);
    float t3 = fmaxf(sf[0][3], sf[1][3]);
    #pragma unroll
    for (int r = 4; r < 16; r += 4) {
        t0 = fmaxf(t0, fmaxf(sf[0][r],     sf[1][r]));
        t1 = fmaxf(t1, fmaxf(sf[0][r + 1], sf[1][r + 1]));
        t2 = fmaxf(t2, fmaxf(sf[0][r + 2], sf[1][r + 2]));
        t3 = fmaxf(t3, fmaxf(sf[0][r + 3], sf[1][r + 3]));
    }
    float pm = fmaxf(fmaxf(t0, t1), fmaxf(t2, t3));
    pm = fmaxf(pm, __shfl_xor(pm, 32));

    float mn = s.m;
    if (__any(pm > s.m)) {
        mn = fmaxf(s.m, pm);
        const float sc = exp2f(s.m - mn);
        s.m = mn;
        s.l *= sc;
        #pragma unroll
        for (int ct = 0; ct < 2; ++ct)
            #pragma unroll
            for (int r = 0; r < 16; ++r) s.acc[ct][r] *= sc;
    }

    float s0a = 0.f, s1a = 0.f, s2a = 0.f, s3a = 0.f;
    #pragma unroll
    for (int f = 0; f < 2; ++f)
        #pragma unroll
        for (int r = 0; r < 16; r += 4) {
            float p0 = exp2f(sf[f][r] - mn);
            float p1 = exp2f(sf[f][r + 1] - mn);
            float p2 = exp2f(sf[f][r + 2] - mn);
            float p3 = exp2f(sf[f][r + 3] - mn);
            sf[f][r] = p0; sf[f][r + 1] = p1; sf[f][r + 2] = p2; sf[f][r + 3] = p3;
            s0a += p0; s1a += p1; s2a += p2; s3a += p3;
        }
    float rs = (s0a + s1a) + (s2a + s3a);
    rs += __shfl_xor(rs, 32);
    s.l += rs;

    #pragma unroll
    for (int f = 0; f < 2; ++f) {
        unsigned w01 = cvtpk(sf[f][0], sf[f][1]);
        unsigned w23 = cvtpk(sf[f][2], sf[f][3]);
        unsigned w45 = cvtpk(sf[f][4], sf[f][5]);
        unsigned w67 = cvtpk(sf[f][6], sf[f][7]);
        pls(w01, w45); pls(w23, w67);
        union { unsigned uu[4]; bf16x8 v; } pa0, pa1;
        pa0.uu[0] = w01; pa0.uu[1] = w23; pa0.uu[2] = w45; pa0.uu[3] = w67;
        unsigned x01 = cvtpk(sf[f][8],  sf[f][9]);
        unsigned x23 = cvtpk(sf[f][10], sf[f][11]);
        unsigned x45 = cvtpk(sf[f][12], sf[f][13]);
        unsigned x67 = cvtpk(sf[f][14], sf[f][15]);
        pls(x01, x45); pls(x23, x67);
        pa1.uu[0] = x01; pa1.uu[1] = x23; pa1.uu[2] = x45; pa1.uu[3] = x67;
        __builtin_amdgcn_s_setprio(1);
        #pragma unroll
        for (int ct = 0; ct < 2; ++ct) {
            s.acc[ct] = __builtin_amdgcn_mfma_f32_32x32x16_bf16(vf[2 * f][ct],     pa0.v, s.acc[ct], 0, 0, 0);
            s.acc[ct] = __builtin_amdgcn_mfma_f32_32x32x16_bf16(vf[2 * f + 1][ct], pa1.v, s.acc[ct], 0, 0, 0);
        }
        __builtin_amdgcn_s_setprio(0);
    }
}

// ---- Kernel 2: REAL attn (R22 byte-identical) ------------------------------
__global__ __launch_bounds__(512)
__attribute__((amdgpu_waves_per_eu(2, 2)))
void attn_kernel(
    const unsigned short* __restrict__ Qp, const unsigned short* __restrict__ Kp,
    const unsigned short* __restrict__ Vp, float* __restrict__ out)
{
    __shared__ float accbuf[8][32][68];
    __shared__ float mbuf[8][32], lbuf[8][32];

    const int tid = threadIdx.x, w = tid >> 6, lane = tid & 63;
    const int c = lane & 31, h = lane >> 5;
    const int b = blockIdx.x & 3;
    const int pp = blockIdx.x >> 2;

    const unsigned short* __restrict__ Qpb = Qp + (size_t)b * 128 * 4 * 512;
    const unsigned short* __restrict__ Kpb = Kp + (size_t)b * 64 * 8 * 512;
    const unsigned short* __restrict__ Vpb = Vp + (size_t)b * 64 * 8 * 512;

    TS A, Bt;
    tile_init(A,  127 - pp, Qpb, lane);
    tile_init(Bt, pp,       Qpb, lane);
    const int ncA = ((A.qb  + 31) >> 6) + 1;
    const int ncB = ((Bt.qb + 31) >> 6) + 1;
    const int itA = (ncA > w) ? ((ncA - w + 7) >> 3) : 0;
    const int itB = (ncB > w) ? ((ncB - w + 7) >> 3) : 0;

    const unsigned short* kptr = Kpb + (size_t)w * 4096 + lane * 8;
    const unsigned short* vptr = Vpb + (size_t)w * 4096 + lane * 8;

    for (int i = 0; i < itA; ++i) {
        const int s0 = (w + i * 8) << 6;
        bf16x8 kf[2][4];
        #pragma unroll
        for (int f = 0; f < 2; ++f)
            #pragma unroll
            for (int kk = 0; kk < 4; ++kk)
                kf[f][kk] = *(const bf16x8*)&kptr[f * 2048 + kk * 512];
        bf16x8 vf[4][2];
        #pragma unroll
        for (int ks = 0; ks < 4; ++ks)
            #pragma unroll
            for (int ct = 0; ct < 2; ++ct)
                vf[ks][ct] = *(const bf16x8*)&vptr[ks * 1024 + ct * 512];

        tile_compute(A, kf, vf, s0, h, c);
        if (i < itB) tile_compute(Bt, kf, vf, s0, h, c);

        kptr += 32768;
        vptr += 32768;
    }

    #pragma unroll
    for (int which = 0; which < 2; ++which) {
        if (which == 0) {
            if (h == 0) { mbuf[w][c] = A.m; lbuf[w][c] = A.l; }
            #pragma unroll
            for (int ct = 0; ct < 2; ++ct)
                #pragma unroll
                for (int g = 0; g < 4; ++g)
                    *(float4*)&accbuf[w][c][ct * 32 + g * 8 + 4 * h] =
                        make_float4(A.acc[ct][4 * g], A.acc[ct][4 * g + 1],
                                    A.acc[ct][4 * g + 2], A.acc[ct][4 * g + 3]);
        } else {
            if (h == 0) { mbuf[w][c] = Bt.m; lbuf[w][c] = Bt.l; }
            #pragma unroll
            for (int ct = 0; ct < 2; ++ct)
                #pragma unroll
                for (int g = 0; g < 4; ++g)
                    *(float4*)&accbuf[w][c][ct * 32 + g * 8 + 4 * h] =
                        make_float4(Bt.acc[ct][4 * g], Bt.acc[ct][4 * g + 1],
                                    Bt.acc[ct][4 * g + 2], Bt.acc[ct][4 * g + 3]);
        }
        __syncthreads();
        const int qb = which ? (pp << 5) : ((127 - pp) << 5);
        #pragma unroll
        for (int i = 0; i < 4; ++i) {
            const int e = tid + i * 512;
            const int q = e >> 6, d = e & 63;
            float ms = mbuf[0][q];
            #pragma unroll
            for (int wv = 1; wv < 8; ++wv) ms = fmaxf(ms, mbuf[wv][q]);
            float ls = 0.f, os = 0.f;
            #pragma unroll
            for (int wv = 0; wv < 8; ++wv) {
                const float e_ = exp2f(mbuf[wv][q] - ms);
                ls += lbuf[wv][q] * e_;
                os += accbuf[wv][q][d] * e_;
            }
            out[((long)b * T_ + qb + q) * 64 + d] = os / ls;
        }
        __syncthreads();
    }
}

// ---- ABLATION kernels: MODE 0=full 1=noSM 2=noPV 3=loads-only, x8 reps -----
// Writes to ws scratch. Serial rep dependence via data-dependent offset
// (red is never >1e30 at runtime; compiler can't prove it) -> no cross-rep CSE.
template<int MODE>
__global__ __launch_bounds__(512)
__attribute__((amdgpu_waves_per_eu(2, 2)))
void attn_abl(
    const unsigned short* __restrict__ Qp, const unsigned short* __restrict__ Kp,
    const unsigned short* __restrict__ Vp, float* __restrict__ scratch)
{
    const int tid = threadIdx.x, w = tid >> 6, lane = tid & 63;
    const int c = lane & 31, h = lane >> 5;
    const int b = blockIdx.x & 3;
    const int pp = blockIdx.x >> 2;

    const unsigned short* __restrict__ Qpb = Qp + (size_t)b * 128 * 4 * 512;
    const unsigned short* __restrict__ Kpb = Kp + (size_t)b * 64 * 8 * 512;
    const unsigned short* __restrict__ Vpb = Vp + (size_t)b * 64 * 8 * 512;

    const int qbA = (127 - pp) << 5, qbB = pp << 5;
    const int ncA = ((qbA + 31) >> 6) + 1;
    const int ncB = ((qbB + 31) >> 6) + 1;
    const int itA = (ncA > w) ? ((ncA - w + 7) >> 3) : 0;
    const int itB = (ncB > w) ? ((ncB - w + 7) >> 3) : 0;

    float red = 0.f;
    #pragma unroll 1
    for (int rep = 0; rep < 8; ++rep) {
        TS A, Bt;
        tile_init(A,  127 - pp, Qpb, lane);
        tile_init(Bt, pp,       Qpb, lane);
        // data-dependent (always 0) offset: forces serial reps, defeats CSE
        const size_t dep = (red > 1e30f) ? 64 : 0;
        const unsigned short* kptr = Kpb + (size_t)w * 4096 + lane * 8 + dep;
        const unsigned short* vptr = Vpb + (size_t)w * 4096 + lane * 8 + dep;

        #pragma unroll 1
        for (int i = 0; i < itA; ++i) {
            const int s0 = (w + i * 8) << 6;
            bf16x8 kf[2][4];
            #pragma unroll
            for (int f = 0; f < 2; ++f)
                #pragma unroll
                for (int kk = 0; kk < 4; ++kk)
                    kf[f][kk] = *(const bf16x8*)&kptr[f * 2048 + kk * 512];
            bf16x8 vf[4][2];
            #pragma unroll
            for (int ks = 0; ks < 4; ++ks)
                #pragma unroll
                for (int ct = 0; ct < 2; ++ct)
                    vf[ks][ct] = *(const bf16x8*)&vptr[ks * 1024 + ct * 512];

            if constexpr (MODE == 3) {
                // loads only: keep kf/vf live with cheap adds
                #pragma unroll
                for (int f = 0; f < 2; ++f)
                    #pragma unroll
                    for (int kk = 0; kk < 4; ++kk) red += (float)kf[f][kk][0];
                #pragma unroll
                for (int ks = 0; ks < 4; ++ks)
                    #pragma unroll
                    for (int ct = 0; ct < 2; ++ct) red += (float)vf[ks][ct][0];
            } else if constexpr (MODE == 0) {
                tile_compute(A, kf, vf, s0, h, c);
                if (i < itB) tile_compute(Bt, kf, vf, s0, h, c);
            } else {
                // MODE 1 (noSM) / MODE 2 (noPV): inline variant body, tile A + B
                #pragma unroll
                for (int which = 0; which < 2; ++which) {
                    if (which == 1 && i >= itB) break;
                    TS& s = which ? Bt : A;
                    f32x16 sf[2];
                    #pragma unroll
                    for (int f = 0; f < 2; ++f)
                        #pragma unroll
                        for (int j = 0; j < 16; ++j) sf[f][j] = 0.f;
                    __builtin_amdgcn_s_setprio(1);
                    #pragma unroll
                    for (int f = 0; f < 2; ++f)
                        #pragma unroll
                        for (int kk = 0; kk < 4; ++kk)
                            sf[f] = __builtin_amdgcn_mfma_f32_32x32x16_bf16(kf[f][kk], s.qf[kk], sf[f], 0, 0, 0);
                    __builtin_amdgcn_s_setprio(0);
                    if (s0 + 63 > s.qb) {
                        #pragma unroll
                        for (int f = 0; f < 2; ++f)
                            #pragma unroll
                            for (int r = 0; r < 16; ++r) {
                                const int key = s0 + f * 32 + ((r & 3) + 8 * (r >> 2)) + 4 * h;
                                if (key > s.qb + c) sf[f][r] = (MODE == 1) ? 0.f : -1e30f;
                            }
                    }
                    float mn = 0.f;
                    if constexpr (MODE == 2) {
                        // full softmax, then keep p-values live via rs -> acc
                        float t0 = fmaxf(sf[0][0], sf[1][0]);
                        float t1 = fmaxf(sf[0][1], sf[1][1]);
                        float t2 = fmaxf(sf[0][2], sf[1][2]);
                        float t3 = fmaxf(sf[0][3], sf[1][3]);
                        #pragma unroll
                        for (int r = 4; r < 16; r += 4) {
                            t0 = fmaxf(t0, fmaxf(sf[0][r],     sf[1][r]));
                            t1 = fmaxf(t1, fmaxf(sf[0][r + 1], sf[1][r + 1]));
                            t2 = fmaxf(t2, fmaxf(sf[0][r + 2], sf[1][r + 2]));
                            t3 = fmaxf(t3, fmaxf(sf[0][r + 3], sf[1][r + 3]));
                        }
                        float pm = fmaxf(fmaxf(t0, t1), fmaxf(t2, t3));
                        pm = fmaxf(pm, __shfl_xor(pm, 32));
                        mn = s.m;
                        if (__any(pm > s.m)) {
                            mn = fmaxf(s.m, pm);
                            const float sc = exp2f(s.m - mn);
                            s.m = mn;
                            s.l *= sc;
                            #pragma unroll
                            for (int ct = 0; ct < 2; ++ct)
                                #pragma unroll
                                for (int r = 0; r < 16; ++r) s.acc[ct][r] *= sc;
                        }
                        float s0a = 0.f, s1a = 0.f, s2a = 0.f, s3a = 0.f;
                        #pragma unroll
                        for (int f = 0; f < 2; ++f)
                            #pragma unroll
                            for (int r = 0; r < 16; r += 4) {
                                s0a += exp2f(sf[f][r] - mn);
                                s1a += exp2f(sf[f][r + 1] - mn);
                                s2a += exp2f(sf[f][r + 2] - mn);
                                s3a += exp2f(sf[f][r + 3] - mn);
                            }
                        float rs = (s0a + s1a) + (s2a + s3a);
                        rs += __shfl_xor(rs, 32);
                        s.l += rs;
                        s.acc[0][0] += rs;   // keep exp chain live
                        // vf kept live cheaply (counted in load phase)
                        #pragma unroll
                        for (int ks = 0; ks < 4; ++ks) red += (float)vf[ks][0][0];
                    } else {
                        // MODE 1: no softmax — raw sf feeds pack+PV directly
                        #pragma unroll
                        for (int f = 0; f < 2; ++f) {
                            unsigned w01 = cvtpk(sf[f][0], sf[f][1]);
                            unsigned w23 = cvtpk(sf[f][2], sf[f][3]);
                            unsigned w45 = cvtpk(sf[f][4], sf[f][5]);
                            unsigned w67 = cvtpk(sf[f][6], sf[f][7]);
                            pls(w01, w45); pls(w23, w67);
                            union { unsigned uu[4]; bf16x8 v; } pa0, pa1;
                            pa0.uu[0] = w01; pa0.uu[1] = w23; pa0.uu[2] = w45; pa0.uu[3] = w67;
                            unsigned x01 = cvtpk(sf[f][8],  sf[f][9]);
                            unsigned x23 = cvtpk(sf[f][10], sf[f][11]);
                            unsigned x45 = cvtpk(sf[f][12], sf[f][13]);
                            unsigned x67 = cvtpk(sf[f][14], sf[f][15]);
                            pls(x01, x45); pls(x23, x67);
                            pa1.uu[0] = x01; pa1.uu[1] = x23; pa1.uu[2] = x45; pa1.uu[3] = x67;
                            __builtin_amdgcn_s_setprio(1);
                            #pragma unroll
                            for (int ct = 0; ct < 2; ++ct) {
                                s.acc[ct] = __builtin_amdgcn_mfma_f32_32x32x16_bf16(vf[2 * f][ct],     pa0.v, s.acc[ct], 0, 0, 0);
                                s.acc[ct] = __builtin_amdgcn_mfma_f32_32x32x16_bf16(vf[2 * f + 1][ct], pa1.v, s.acc[ct], 0, 0, 0);
                            }
                            __builtin_amdgcn_s_setprio(0);
                        }
                    }
                }
            }
            kptr += 32768;
            vptr += 32768;
        }
        // fold per-rep state into red (keeps everything live across reps)
        #pragma unroll
        for (int ct = 0; ct < 2; ++ct)
            #pragma unroll
            for (int j = 0; j < 16; ++j) red += A.acc[ct][j] + Bt.acc[ct][j];
        red += A.l + Bt.l + A.m * 1e-30f + Bt.m * 1e-30f;
    }
    scratch[(size_t)blockIdx.x * 512 + tid] = red;
}

extern "C" void kernel_launch(void* const* d_in, const int* in_sizes, int n_in,
                              void* d_out, int out_size, void* d_ws, size_t ws_size,
                              hipStream_t stream)
{
    const float* emb = (const float*)d_in[0];
    const float* Wq  = (const float*)d_in[1];
    const float* Wk  = (const float*)d_in[2];
    const float* Wv  = (const float*)d_in[3];
    float* out = (float*)d_out;

    unsigned short* Qp = (unsigned short*)d_ws;
    unsigned short* Kp = Qp + (size_t)B_ * T_ * A_;
    unsigned short* Vp = Kp + (size_t)B_ * T_ * A_;
    unsigned short* Wp = Vp + (size_t)B_ * T_ * A_;
    float* scratch = (float*)(Wp + 12288 * 8);          // 512 KB ablation scratch

    prep_w<<<dim3(48), dim3(256), 0, stream>>>(Wq, Wk, Wv, Wp);
    qkv_proj_kernel<<<dim3(512), dim3(768), 0, stream>>>(emb, Wp, Qp, Kp, Vp);
    attn_kernel<<<dim3(256), dim3(512), 0, stream>>>(Qp, Kp, Vp, out);
    // MEASUREMENT: phase ablation, x8 reps each -> direct dur_us in top-5.
    attn_abl<0><<<dim3(256), dim3(512), 0, stream>>>(Qp, Kp, Vp, scratch);
    attn_abl<1><<<dim3(256), dim3(512), 0, stream>>>(Qp, Kp, Vp, scratch);
    attn_abl<2><<<dim3(256), dim3(512), 0, stream>>>(Qp, Kp, Vp, scratch);
    attn_abl<3><<<dim3(256), dim3(512), 0, stream>>>(Qp, Kp, Vp, scratch);
}

// Round 24
// 43.848 us; speedup vs baseline: 11.0527x; 11.0527x over previous
//
#include <hip/hip_runtime.h>

#define B_ 4
#define T_ 4096
#define E_ 512
#define A_ 64
#define SQSCALE 0.1803368801111204f   // log2(e)/8 : folds softmax scale + exp->exp2

typedef __attribute__((ext_vector_type(8)))  short bf16x8;
typedef __attribute__((ext_vector_type(8)))  unsigned short ushort8;
typedef __attribute__((ext_vector_type(4)))  unsigned int   u32x4;
typedef __attribute__((ext_vector_type(4)))  float f32x4;
typedef __attribute__((ext_vector_type(16))) float f32x16;

__device__ __forceinline__ unsigned short f2bf(float x) {
    union { float f; unsigned int u; } v; v.f = x;
    unsigned int r = v.u + 0x7fffu + ((v.u >> 16) & 1u);
    return (unsigned short)(r >> 16);
}
__device__ __forceinline__ unsigned cvtpk(float a, float b) {
    unsigned r;
    asm("v_cvt_pk_bf16_f32 %0, %1, %2" : "=v"(r) : "v"(a), "v"(b));
    return r;
}
__device__ __forceinline__ void pls(unsigned &a, unsigned &b) {
    asm("v_permlane32_swap_b32 %0, %1" : "+v"(a), "+v"(b));
}

// ---- Kernel 0: W -> Wp, fragment-packed bf16 B-frags [nt 12][ks 16][lane 64]x8
__global__ __launch_bounds__(256) void prep_w(
    const float* __restrict__ Wq, const float* __restrict__ Wk,
    const float* __restrict__ Wv, unsigned short* __restrict__ Wp)
{
    const int e = blockIdx.x * 256 + threadIdx.x;
    const int ks = (e >> 6) & 15;
    const int nt = e >> 10;
    const int l  = e & 63;
    const int col = nt * 16 + (l & 15);
    const int kb  = ks * 32 + (l >> 4) * 8;
    const float* W = (col < 64) ? Wq : ((col < 128) ? Wk : Wv);
    const int cc = col & 63;
    const float sc = (col < 64) ? SQSCALE : 1.f;
    union { unsigned short s[8]; ushort8 v; } u;
    #pragma unroll
    for (int j = 0; j < 8; ++j) u.s[j] = f2bf(W[(kb + j) * 64 + cc] * sc);
    *(ushort8*)&Wp[(size_t)e * 8] = u.v;
}

// ---- Kernel 1: QKV projection via bf16 MFMA (R17 version, byte-identical) --
__global__ __launch_bounds__(768, 4) void qkv_proj_kernel(
    const float* __restrict__ emb, const unsigned short* __restrict__ Wp,
    unsigned short* __restrict__ Qp, unsigned short* __restrict__ Kp,
    unsigned short* __restrict__ Vp)
{
    __shared__ unsigned short at[32][536];
    __shared__ unsigned short qt[32][72];
    __shared__ unsigned short kt[32][72];
    __shared__ unsigned short vt[64][40];
    const int tid = threadIdx.x;
    const long row0 = (long)blockIdx.x * 32;

    if (tid < 512) {
        const int r = tid >> 4, c16 = tid & 15;
        const float* __restrict__ src = emb + (row0 + r) * 512;
        #pragma unroll
        for (int j = 0; j < 4; ++j) {
            const int col = j * 128 + c16 * 8;
            const float4 x0 = *(const float4*)(src + col);
            const float4 x1 = *(const float4*)(src + col + 4);
            u32x4 p;
            p[0] = cvtpk(x0.x, x0.y); p[1] = cvtpk(x0.z, x0.w);
            p[2] = cvtpk(x1.x, x1.y); p[3] = cvtpk(x1.z, x1.w);
            *(u32x4*)&at[r][col] = p;
        }
    }
    __syncthreads();

    const int w = tid >> 6, lane = tid & 63;
    const int c = lane & 15, hi = lane >> 4;

    f32x4 acc[2];
    acc[0] = (f32x4){0.f, 0.f, 0.f, 0.f};
    acc[1] = (f32x4){0.f, 0.f, 0.f, 0.f};

    #pragma unroll
    for (int ks = 0; ks < 16; ++ks) {
        const bf16x8 bf_ = *(const bf16x8*)&Wp[((size_t)(w * 16 + ks) * 64 + lane) * 8];
        const bf16x8 a0 = *(const bf16x8*)&at[c][ks * 32 + hi * 8];
        const bf16x8 a1 = *(const bf16x8*)&at[16 + c][ks * 32 + hi * 8];
        acc[0] = __builtin_amdgcn_mfma_f32_16x16x32_bf16(a0, bf_, acc[0], 0, 0, 0);
        acc[1] = __builtin_amdgcn_mfma_f32_16x16x32_bf16(a1, bf_, acc[1], 0, 0, 0);
    }

    #pragma unroll
    for (int rr = 0; rr < 2; ++rr)
        #pragma unroll
        for (int r4 = 0; r4 < 4; ++r4) {
            const int rloc = rr * 16 + hi * 4 + r4;
            const unsigned short v = f2bf(acc[rr][r4]);
            if (w < 4)       qt[rloc][w * 16 + c] = v;
            else if (w < 8)  kt[rloc][(w - 4) * 16 + c] = v;
            else             vt[(w - 8) * 16 + c][rloc] = v;
        }
    __syncthreads();

    const int tloc = (int)(row0 & 4095);
    const long bb = row0 >> 12;
    const int ci  = tloc >> 6;
    const int f_  = (tloc >> 5) & 1;
    const int ks0 = (tloc >> 4) & 3;
    const int tt  = tloc >> 5;
    if (tid < 256) {
        const int kk = tid >> 6, l = tid & 63;
        const ushort8 kval = *(const ushort8*)&kt[l & 31][kk * 16 + (l >> 5) * 8];
        *(ushort8*)&Kp[((((bb * 64 + ci) * 2 + f_) * 4 + kk) * 64 + l) * 8] = kval;
        const ushort8 qval = *(const ushort8*)&qt[l & 31][kk * 16 + (l >> 5) * 8];
        *(ushort8*)&Qp[(((bb * 128 + tt) * 4 + kk) * 64 + l) * 8] = qval;
    } else if (tid < 512) {
        const int e = tid - 256;
        const int ksl = e >> 7, ct = (e >> 6) & 1, l = e & 63;
        const ushort8 val = *(const ushort8*)&vt[ct * 32 + (l & 31)][ksl * 16 + (l >> 5) * 8];
        *(ushort8*)&Vp[((((bb * 64 + ci) * 4 + ks0 + ksl) * 2 + ct) * 64 + l) * 8] = val;
    }
}

// ---- shared tile structs (R22 byte-identical) ------------------------------
struct TS {
    bf16x8 qf[4];
    f32x16 acc[2];
    float m, l;
    int qb;
};

__device__ __forceinline__ void tile_init(TS& s, int t,
    const unsigned short* __restrict__ Qpb, int lane)
{
    s.qb = t << 5;
    #pragma unroll
    for (int kk = 0; kk < 4; ++kk)
        s.qf[kk] = *(const bf16x8*)&Qpb[(((size_t)t * 4 + kk) * 64 + lane) * 8];
    #pragma unroll
    for (int ct = 0; ct < 2; ++ct)
        #pragma unroll
        for (int j = 0; j < 16; ++j) s.acc[ct][j] = 0.f;
    s.m = -1e30f; s.l = 0.f;
}

__device__ __forceinline__ void tile_compute(TS& s, const bf16x8 kf[2][4],
    const bf16x8 vf[4][2], int s0, int h, int c)
{
    f32x16 sf[2];
    #pragma unroll
    for (int f = 0; f < 2; ++f)
        #pragma unroll
        for (int j = 0; j < 16; ++j) sf[f][j] = 0.f;
    __builtin_amdgcn_s_setprio(1);
    #pragma unroll
    for (int f = 0; f < 2; ++f)
        #pragma unroll
        for (int kk = 0; kk < 4; ++kk)
            sf[f] = __builtin_amdgcn_mfma_f32_32x32x16_bf16(kf[f][kk], s.qf[kk], sf[f], 0, 0, 0);
    __builtin_amdgcn_s_setprio(0);

    if (s0 + 63 > s.qb) {
        #pragma unroll
        for (int f = 0; f < 2; ++f)
            #pragma unroll
            for (int r = 0; r < 16; ++r) {
                const int key = s0 + f * 32 + ((r & 3) + 8 * (r >> 2)) + 4 * h;
                if (key > s.qb + c) sf[f][r] = -1e30f;
            }
    }

    float t0 = fmaxf(sf[0][0], sf[1][0]);
    float t1 = fmaxf(sf[0][1], sf[1][1]);
    float t2 = fmaxf(sf[0][2], sf[1][2]);
    float t3 = fmaxf(sf[0][3], sf[1][3]);
    #pragma unroll
    for (int r = 4; r < 16; r += 4) {
        t0 = fmaxf(t0, fmaxf(sf[0][r],     sf[1][r]));
        t1 = fmaxf(t1, fmaxf(sf[0][r + 1], sf[1][r + 1]));
        t2 = fmaxf(t2, fmaxf(sf[0][r + 2], sf[1][r + 2]));
        t3 = fmaxf(t3, fmaxf(sf[0][r + 3], sf[1][r + 3]));
    }
    float pm = fmaxf(fmaxf(t0, t1), fmaxf(t2, t3));
    pm = fmaxf(pm, __shfl_xor(pm, 32));

    float mn = s.m;
    if (__any(pm > s.m)) {
        mn = fmaxf(s.m, pm);
        const float sc = exp2f(s.m - mn);
        s.m = mn;
        s.l *= sc;
        #pragma unroll
        for (int ct = 0; ct < 2; ++ct)
            #pragma unroll
            for (int r = 0; r < 16; ++r) s.acc[ct][r] *= sc;
    }

    float s0a = 0.f, s1a = 0.f, s2a = 0.f, s3a = 0.f;
    #pragma unroll
    for (int f = 0; f < 2; ++f)
        #pragma unroll
        for (int r = 0; r < 16; r += 4) {
            float p0 = exp2f(sf[f][r] - mn);
            float p1 = exp2f(sf[f][r + 1] - mn);
            float p2 = exp2f(sf[f][r + 2] - mn);
            float p3 = exp2f(sf[f][r + 3] - mn);
            sf[f][r] = p0; sf[f][r + 1] = p1; sf[f][r + 2] = p2; sf[f][r + 3] = p3;
            s0a += p0; s1a += p1; s2a += p2; s3a += p3;
        }
    float rs = (s0a + s1a) + (s2a + s3a);
    rs += __shfl_xor(rs, 32);
    s.l += rs;

    #pragma unroll
    for (int f = 0; f < 2; ++f) {
        unsigned w01 = cvtpk(sf[f][0], sf[f][1]);
        unsigned w23 = cvtpk(sf[f][2], sf[f][3]);
        unsigned w45 = cvtpk(sf[f][4], sf[f][5]);
        unsigned w67 = cvtpk(sf[f][6], sf[f][7]);
        pls(w01, w45); pls(w23, w67);
        union { unsigned uu[4]; bf16x8 v; } pa0, pa1;
        pa0.uu[0] = w01; pa0.uu[1] = w23; pa0.uu[2] = w45; pa0.uu[3] = w67;
        unsigned x01 = cvtpk(sf[f][8],  sf[f][9]);
        unsigned x23 = cvtpk(sf[f][10], sf[f][11]);
        unsigned x45 = cvtpk(sf[f][12], sf[f][13]);
        unsigned x67 = cvtpk(sf[f][14], sf[f][15]);
        pls(x01, x45); pls(x23, x67);
        pa1.uu[0] = x01; pa1.uu[1] = x23; pa1.uu[2] = x45; pa1.uu[3] = x67;
        __builtin_amdgcn_s_setprio(1);
        #pragma unroll
        for (int ct = 0; ct < 2; ++ct) {
            s.acc[ct] = __builtin_amdgcn_mfma_f32_32x32x16_bf16(vf[2 * f][ct],     pa0.v, s.acc[ct], 0, 0, 0);
            s.acc[ct] = __builtin_amdgcn_mfma_f32_32x32x16_bf16(vf[2 * f + 1][ct], pa1.v, s.acc[ct], 0, 0, 0);
        }
        __builtin_amdgcn_s_setprio(0);
    }
}

// ---- Kernel 2: causal flash attention, ILP-2 shared loads ------------------
// R22 body. Attribute fix: NO __launch_bounds__ (its occupancy heuristic
// overrode waves_per_eu in R21-R23 -> VGPR capped 128 -> spill); explicit
// flat_work_group_size(512,512) + waves_per_eu(2,2) hands the allocator a
// 512/2 = 256-VGPR budget for exactly 2 waves/SIMD.
__global__ __attribute__((amdgpu_flat_work_group_size(512, 512), amdgpu_waves_per_eu(2, 2)))
void attn_kernel(
    const unsigned short* __restrict__ Qp, const unsigned short* __restrict__ Kp,
    const unsigned short* __restrict__ Vp, float* __restrict__ out)
{
    __shared__ float accbuf[8][32][68];
    __shared__ float mbuf[8][32], lbuf[8][32];

    const int tid = threadIdx.x, w = tid >> 6, lane = tid & 63;
    const int c = lane & 31, h = lane >> 5;
    const int b = blockIdx.x & 3;
    const int pp = blockIdx.x >> 2;

    const unsigned short* __restrict__ Qpb = Qp + (size_t)b * 128 * 4 * 512;
    const unsigned short* __restrict__ Kpb = Kp + (size_t)b * 64 * 8 * 512;
    const unsigned short* __restrict__ Vpb = Vp + (size_t)b * 64 * 8 * 512;

    TS A, Bt;
    tile_init(A,  127 - pp, Qpb, lane);
    tile_init(Bt, pp,       Qpb, lane);
    const int ncA = ((A.qb  + 31) >> 6) + 1;
    const int ncB = ((Bt.qb + 31) >> 6) + 1;
    const int itA = (ncA > w) ? ((ncA - w + 7) >> 3) : 0;
    const int itB = (ncB > w) ? ((ncB - w + 7) >> 3) : 0;

    const unsigned short* kptr = Kpb + (size_t)w * 4096 + lane * 8;
    const unsigned short* vptr = Vpb + (size_t)w * 4096 + lane * 8;

    for (int i = 0; i < itA; ++i) {
        const int s0 = (w + i * 8) << 6;
        bf16x8 kf[2][4];
        #pragma unroll
        for (int f = 0; f < 2; ++f)
            #pragma unroll
            for (int kk = 0; kk < 4; ++kk)
                kf[f][kk] = *(const bf16x8*)&kptr[f * 2048 + kk * 512];
        bf16x8 vf[4][2];
        #pragma unroll
        for (int ks = 0; ks < 4; ++ks)
            #pragma unroll
            for (int ct = 0; ct < 2; ++ct)
                vf[ks][ct] = *(const bf16x8*)&vptr[ks * 1024 + ct * 512];

        tile_compute(A, kf, vf, s0, h, c);
        if (i < itB) tile_compute(Bt, kf, vf, s0, h, c);

        kptr += 32768;
        vptr += 32768;
    }

    #pragma unroll
    for (int which = 0; which < 2; ++which) {
        if (which == 0) {
            if (h == 0) { mbuf[w][c] = A.m; lbuf[w][c] = A.l; }
            #pragma unroll
            for (int ct = 0; ct < 2; ++ct)
                #pragma unroll
                for (int g = 0; g < 4; ++g)
                    *(float4*)&accbuf[w][c][ct * 32 + g * 8 + 4 * h] =
                        make_float4(A.acc[ct][4 * g], A.acc[ct][4 * g + 1],
                                    A.acc[ct][4 * g + 2], A.acc[ct][4 * g + 3]);
        } else {
            if (h == 0) { mbuf[w][c] = Bt.m; lbuf[w][c] = Bt.l; }
            #pragma unroll
            for (int ct = 0; ct < 2; ++ct)
                #pragma unroll
                for (int g = 0; g < 4; ++g)
                    *(float4*)&accbuf[w][c][ct * 32 + g * 8 + 4 * h] =
                        make_float4(Bt.acc[ct][4 * g], Bt.acc[ct][4 * g + 1],
                                    Bt.acc[ct][4 * g + 2], Bt.acc[ct][4 * g + 3]);
        }
        __syncthreads();
        const int qb = which ? (pp << 5) : ((127 - pp) << 5);
        #pragma unroll
        for (int i = 0; i < 4; ++i) {
            const int e = tid + i * 512;
            const int q = e >> 6, d = e & 63;
            float ms = mbuf[0][q];
            #pragma unroll
            for (int wv = 1; wv < 8; ++wv) ms = fmaxf(ms, mbuf[wv][q]);
            float ls = 0.f, os = 0.f;
            #pragma unroll
            for (int wv = 0; wv < 8; ++wv) {
                const float e_ = exp2f(mbuf[wv][q] - ms);
                ls += lbuf[wv][q] * e_;
                os += accbuf[wv][q][d] * e_;
            }
            out[((long)b * T_ + qb + q) * 64 + d] = os / ls;
        }
        __syncthreads();
    }
}

extern "C" void kernel_launch(void* const* d_in, const int* in_sizes, int n_in,
                              void* d_out, int out_size, void* d_ws, size_t ws_size,
                              hipStream_t stream)
{
    const float* emb = (const float*)d_in[0];
    const float* Wq  = (const float*)d_in[1];
    const float* Wk  = (const float*)d_in[2];
    const float* Wv  = (const float*)d_in[3];
    float* out = (float*)d_out;

    unsigned short* Qp = (unsigned short*)d_ws;
    unsigned short* Kp = Qp + (size_t)B_ * T_ * A_;
    unsigned short* Vp = Kp + (size_t)B_ * T_ * A_;
    unsigned short* Wp = Vp + (size_t)B_ * T_ * A_;

    prep_w<<<dim3(48), dim3(256), 0, stream>>>(Wq, Wk, Wv, Wp);
    qkv_proj_kernel<<<dim3(512), dim3(768), 0, stream>>>(emb, Wp, Qp, Kp, Vp);
    attn_kernel<<<dim3(256), dim3(512), 0, stream>>>(Qp, Kp, Vp, out);
}

// Round 25
// 43.553 us; speedup vs baseline: 11.1275x; 1.0068x over previous
//
#include <hip/hip_runtime.h>

#define B_ 4
#define T_ 4096
#define E_ 512
#define A_ 64
#define SQSCALE 0.1803368801111204f   // log2(e)/8 : folds softmax scale + exp->exp2

typedef __attribute__((ext_vector_type(8)))  short bf16x8;
typedef __attribute__((ext_vector_type(8)))  unsigned short ushort8;
typedef __attribute__((ext_vector_type(4)))  unsigned int   u32x4;
typedef __attribute__((ext_vector_type(4)))  float f32x4;
typedef __attribute__((ext_vector_type(16))) float f32x16;

__device__ __forceinline__ unsigned short f2bf(float x) {
    union { float f; unsigned int u; } v; v.f = x;
    unsigned int r = v.u + 0x7fffu + ((v.u >> 16) & 1u);
    return (unsigned short)(r >> 16);
}
__device__ __forceinline__ unsigned cvtpk(float a, float b) {
    unsigned r;
    asm("v_cvt_pk_bf16_f32 %0, %1, %2" : "=v"(r) : "v"(a), "v"(b));
    return r;
}
__device__ __forceinline__ void pls(unsigned &a, unsigned &b) {
    asm("v_permlane32_swap_b32 %0, %1" : "+v"(a), "+v"(b));
}

// ---- Kernel 0: W -> Wp, fragment-packed bf16 B-frags [nt 12][ks 16][lane 64]x8
__global__ __launch_bounds__(256) void prep_w(
    const float* __restrict__ Wq, const float* __restrict__ Wk,
    const float* __restrict__ Wv, unsigned short* __restrict__ Wp)
{
    const int e = blockIdx.x * 256 + threadIdx.x;
    const int ks = (e >> 6) & 15;
    const int nt = e >> 10;
    const int l  = e & 63;
    const int col = nt * 16 + (l & 15);
    const int kb  = ks * 32 + (l >> 4) * 8;
    const float* W = (col < 64) ? Wq : ((col < 128) ? Wk : Wv);
    const int cc = col & 63;
    const float sc = (col < 64) ? SQSCALE : 1.f;
    union { unsigned short s[8]; ushort8 v; } u;
    #pragma unroll
    for (int j = 0; j < 8; ++j) u.s[j] = f2bf(W[(kb + j) * 64 + cc] * sc);
    *(ushort8*)&Wp[(size_t)e * 8] = u.v;
}

// ---- Kernel 1: QKV projection via bf16 MFMA (R17 version, byte-identical) --
__global__ __launch_bounds__(768, 4) void qkv_proj_kernel(
    const float* __restrict__ emb, const unsigned short* __restrict__ Wp,
    unsigned short* __restrict__ Qp, unsigned short* __restrict__ Kp,
    unsigned short* __restrict__ Vp)
{
    __shared__ unsigned short at[32][536];
    __shared__ unsigned short qt[32][72];
    __shared__ unsigned short kt[32][72];
    __shared__ unsigned short vt[64][40];
    const int tid = threadIdx.x;
    const long row0 = (long)blockIdx.x * 32;

    if (tid < 512) {
        const int r = tid >> 4, c16 = tid & 15;
        const float* __restrict__ src = emb + (row0 + r) * 512;
        #pragma unroll
        for (int j = 0; j < 4; ++j) {
            const int col = j * 128 + c16 * 8;
            const float4 x0 = *(const float4*)(src + col);
            const float4 x1 = *(const float4*)(src + col + 4);
            u32x4 p;
            p[0] = cvtpk(x0.x, x0.y); p[1] = cvtpk(x0.z, x0.w);
            p[2] = cvtpk(x1.x, x1.y); p[3] = cvtpk(x1.z, x1.w);
            *(u32x4*)&at[r][col] = p;
        }
    }
    __syncthreads();

    const int w = tid >> 6, lane = tid & 63;
    const int c = lane & 15, hi = lane >> 4;

    f32x4 acc[2];
    acc[0] = (f32x4){0.f, 0.f, 0.f, 0.f};
    acc[1] = (f32x4){0.f, 0.f, 0.f, 0.f};

    #pragma unroll
    for (int ks = 0; ks < 16; ++ks) {
        const bf16x8 bf_ = *(const bf16x8*)&Wp[((size_t)(w * 16 + ks) * 64 + lane) * 8];
        const bf16x8 a0 = *(const bf16x8*)&at[c][ks * 32 + hi * 8];
        const bf16x8 a1 = *(const bf16x8*)&at[16 + c][ks * 32 + hi * 8];
        acc[0] = __builtin_amdgcn_mfma_f32_16x16x32_bf16(a0, bf_, acc[0], 0, 0, 0);
        acc[1] = __builtin_amdgcn_mfma_f32_16x16x32_bf16(a1, bf_, acc[1], 0, 0, 0);
    }

    #pragma unroll
    for (int rr = 0; rr < 2; ++rr)
        #pragma unroll
        for (int r4 = 0; r4 < 4; ++r4) {
            const int rloc = rr * 16 + hi * 4 + r4;
            const unsigned short v = f2bf(acc[rr][r4]);
            if (w < 4)       qt[rloc][w * 16 + c] = v;
            else if (w < 8)  kt[rloc][(w - 4) * 16 + c] = v;
            else             vt[(w - 8) * 16 + c][rloc] = v;
        }
    __syncthreads();

    const int tloc = (int)(row0 & 4095);
    const long bb = row0 >> 12;
    const int ci  = tloc >> 6;
    const int f_  = (tloc >> 5) & 1;
    const int ks0 = (tloc >> 4) & 3;
    const int tt  = tloc >> 5;
    if (tid < 256) {
        const int kk = tid >> 6, l = tid & 63;
        const ushort8 kval = *(const ushort8*)&kt[l & 31][kk * 16 + (l >> 5) * 8];
        *(ushort8*)&Kp[((((bb * 64 + ci) * 2 + f_) * 4 + kk) * 64 + l) * 8] = kval;
        const ushort8 qval = *(const ushort8*)&qt[l & 31][kk * 16 + (l >> 5) * 8];
        *(ushort8*)&Qp[(((bb * 128 + tt) * 4 + kk) * 64 + l) * 8] = qval;
    } else if (tid < 512) {
        const int e = tid - 256;
        const int ksl = e >> 7, ct = (e >> 6) & 1, l = e & 63;
        const ushort8 val = *(const ushort8*)&vt[ct * 32 + (l & 31)][ksl * 16 + (l >> 5) * 8];
        *(ushort8*)&Vp[((((bb * 64 + ci) * 4 + ks0 + ksl) * 2 + ct) * 64 + l) * 8] = val;
    }
}

// ---- shared tile structs (R22 byte-identical) ------------------------------
struct TS {
    bf16x8 qf[4];
    f32x16 acc[2];
    float m, l;
    int qb;
};

__device__ __forceinline__ void tile_init(TS& s, int t,
    const unsigned short* __restrict__ Qpb, int lane)
{
    s.qb = t << 5;
    #pragma unroll
    for (int kk = 0; kk < 4; ++kk)
        s.qf[kk] = *(const bf16x8*)&Qpb[(((size_t)t * 4 + kk) * 64 + lane) * 8];
    #pragma unroll
    for (int ct = 0; ct < 2; ++ct)
        #pragma unroll
        for (int j = 0; j < 16; ++j) s.acc[ct][j] = 0.f;
    s.m = -1e30f; s.l = 0.f;
}

__device__ __forceinline__ void tile_compute(TS& s, const bf16x8 kf[2][4],
    const bf16x8 vf[4][2], int s0, int h, int c)
{
    f32x16 sf[2];
    #pragma unroll
    for (int f = 0; f < 2; ++f)
        #pragma unroll
        for (int j = 0; j < 16; ++j) sf[f][j] = 0.f;
    __builtin_amdgcn_s_setprio(1);
    #pragma unroll
    for (int f = 0; f < 2; ++f)
        #pragma unroll
        for (int kk = 0; kk < 4; ++kk)
            sf[f] = __builtin_amdgcn_mfma_f32_32x32x16_bf16(kf[f][kk], s.qf[kk], sf[f], 0, 0, 0);
    __builtin_amdgcn_s_setprio(0);

    if (s0 + 63 > s.qb) {
        #pragma unroll
        for (int f = 0; f < 2; ++f)
            #pragma unroll
            for (int r = 0; r < 16; ++r) {
                const int key = s0 + f * 32 + ((r & 3) + 8 * (r >> 2)) + 4 * h;
                if (key > s.qb + c) sf[f][r] = -1e30f;
            }
    }

    float t0 = fmaxf(sf[0][0], sf[1][0]);
    float t1 = fmaxf(sf[0][1], sf[1][1]);
    float t2 = fmaxf(sf[0][2], sf[1][2]);
    float t3 = fmaxf(sf[0][3], sf[1][3]);
    #pragma unroll
    for (int r = 4; r < 16; r += 4) {
        t0 = fmaxf(t0, fmaxf(sf[0][r],     sf[1][r]));
        t1 = fmaxf(t1, fmaxf(sf[0][r + 1], sf[1][r + 1]));
        t2 = fmaxf(t2, fmaxf(sf[0][r + 2], sf[1][r + 2]));
        t3 = fmaxf(t3, fmaxf(sf[0][r + 3], sf[1][r + 3]));
    }
    float pm = fmaxf(fmaxf(t0, t1), fmaxf(t2, t3));
    pm = fmaxf(pm, __shfl_xor(pm, 32));

    float mn = s.m;
    if (__any(pm > s.m)) {
        mn = fmaxf(s.m, pm);
        const float sc = exp2f(s.m - mn);
        s.m = mn;
        s.l *= sc;
        #pragma unroll
        for (int ct = 0; ct < 2; ++ct)
            #pragma unroll
            for (int r = 0; r < 16; ++r) s.acc[ct][r] *= sc;
    }

    float s0a = 0.f, s1a = 0.f, s2a = 0.f, s3a = 0.f;
    #pragma unroll
    for (int f = 0; f < 2; ++f)
        #pragma unroll
        for (int r = 0; r < 16; r += 4) {
            float p0 = exp2f(sf[f][r] - mn);
            float p1 = exp2f(sf[f][r + 1] - mn);
            float p2 = exp2f(sf[f][r + 2] - mn);
            float p3 = exp2f(sf[f][r + 3] - mn);
            sf[f][r] = p0; sf[f][r + 1] = p1; sf[f][r + 2] = p2; sf[f][r + 3] = p3;
            s0a += p0; s1a += p1; s2a += p2; s3a += p3;
        }
    float rs = (s0a + s1a) + (s2a + s3a);
    rs += __shfl_xor(rs, 32);
    s.l += rs;

    #pragma unroll
    for (int f = 0; f < 2; ++f) {
        unsigned w01 = cvtpk(sf[f][0], sf[f][1]);
        unsigned w23 = cvtpk(sf[f][2], sf[f][3]);
        unsigned w45 = cvtpk(sf[f][4], sf[f][5]);
        unsigned w67 = cvtpk(sf[f][6], sf[f][7]);
        pls(w01, w45); pls(w23, w67);
        union { unsigned uu[4]; bf16x8 v; } pa0, pa1;
        pa0.uu[0] = w01; pa0.uu[1] = w23; pa0.uu[2] = w45; pa0.uu[3] = w67;
        unsigned x01 = cvtpk(sf[f][8],  sf[f][9]);
        unsigned x23 = cvtpk(sf[f][10], sf[f][11]);
        unsigned x45 = cvtpk(sf[f][12], sf[f][13]);
        unsigned x67 = cvtpk(sf[f][14], sf[f][15]);
        pls(x01, x45); pls(x23, x67);
        pa1.uu[0] = x01; pa1.uu[1] = x23; pa1.uu[2] = x45; pa1.uu[3] = x67;
        __builtin_amdgcn_s_setprio(1);
        #pragma unroll
        for (int ct = 0; ct < 2; ++ct) {
            s.acc[ct] = __builtin_amdgcn_mfma_f32_32x32x16_bf16(vf[2 * f][ct],     pa0.v, s.acc[ct], 0, 0, 0);
            s.acc[ct] = __builtin_amdgcn_mfma_f32_32x32x16_bf16(vf[2 * f + 1][ct], pa1.v, s.acc[ct], 0, 0, 0);
        }
        __builtin_amdgcn_s_setprio(0);
    }
}

// ---- Kernel 2: causal flash attention, ILP-2 + XCD-batch pinning -----------
// R24 body; block remap only: xcd = bid&7, batch = xcd>>1,
// pp = (bid>>3) | ((xcd&1)<<5). Each XCD pair serves ONE batch -> per-XCD
// K/V+Q working set 8 MB -> ~2.5 MB (L2-resident). R23 ablation showed the
// loop is K/V-load-stream-bound at ~14 TB/s (L2-miss -> L3); L2 residency
// raises the ceiling to ~37 TB/s. R12's null was pre-MLP (latency-bound
// regime); the current 2-wave ILP-2 structure is BW-bound (regime rule #23).
__global__ __attribute__((amdgpu_flat_work_group_size(512, 512), amdgpu_waves_per_eu(2, 2)))
void attn_kernel(
    const unsigned short* __restrict__ Qp, const unsigned short* __restrict__ Kp,
    const unsigned short* __restrict__ Vp, float* __restrict__ out)
{
    __shared__ float accbuf[8][32][68];
    __shared__ float mbuf[8][32], lbuf[8][32];

    const int tid = threadIdx.x, w = tid >> 6, lane = tid & 63;
    const int c = lane & 31, h = lane >> 5;
    const int xcd = blockIdx.x & 7;
    const int b = xcd >> 1;                                // batch pinned to XCD pair
    const int pp = (blockIdx.x >> 3) | ((xcd & 1) << 5);   // 0..63, bijective

    const unsigned short* __restrict__ Qpb = Qp + (size_t)b * 128 * 4 * 512;
    const unsigned short* __restrict__ Kpb = Kp + (size_t)b * 64 * 8 * 512;
    const unsigned short* __restrict__ Vpb = Vp + (size_t)b * 64 * 8 * 512;

    TS A, Bt;
    tile_init(A,  127 - pp, Qpb, lane);
    tile_init(Bt, pp,       Qpb, lane);
    const int ncA = ((A.qb  + 31) >> 6) + 1;
    const int ncB = ((Bt.qb + 31) >> 6) + 1;
    const int itA = (ncA > w) ? ((ncA - w + 7) >> 3) : 0;
    const int itB = (ncB > w) ? ((ncB - w + 7) >> 3) : 0;

    const unsigned short* kptr = Kpb + (size_t)w * 4096 + lane * 8;
    const unsigned short* vptr = Vpb + (size_t)w * 4096 + lane * 8;

    for (int i = 0; i < itA; ++i) {
        const int s0 = (w + i * 8) << 6;
        bf16x8 kf[2][4];
        #pragma unroll
        for (int f = 0; f < 2; ++f)
            #pragma unroll
            for (int kk = 0; kk < 4; ++kk)
                kf[f][kk] = *(const bf16x8*)&kptr[f * 2048 + kk * 512];
        bf16x8 vf[4][2];
        #pragma unroll
        for (int ks = 0; ks < 4; ++ks)
            #pragma unroll
            for (int ct = 0; ct < 2; ++ct)
                vf[ks][ct] = *(const bf16x8*)&vptr[ks * 1024 + ct * 512];

        tile_compute(A, kf, vf, s0, h, c);
        if (i < itB) tile_compute(Bt, kf, vf, s0, h, c);

        kptr += 32768;
        vptr += 32768;
    }

    #pragma unroll
    for (int which = 0; which < 2; ++which) {
        if (which == 0) {
            if (h == 0) { mbuf[w][c] = A.m; lbuf[w][c] = A.l; }
            #pragma unroll
            for (int ct = 0; ct < 2; ++ct)
                #pragma unroll
                for (int g = 0; g < 4; ++g)
                    *(float4*)&accbuf[w][c][ct * 32 + g * 8 + 4 * h] =
                        make_float4(A.acc[ct][4 * g], A.acc[ct][4 * g + 1],
                                    A.acc[ct][4 * g + 2], A.acc[ct][4 * g + 3]);
        } else {
            if (h == 0) { mbuf[w][c] = Bt.m; lbuf[w][c] = Bt.l; }
            #pragma unroll
            for (int ct = 0; ct < 2; ++ct)
                #pragma unroll
                for (int g = 0; g < 4; ++g)
                    *(float4*)&accbuf[w][c][ct * 32 + g * 8 + 4 * h] =
                        make_float4(Bt.acc[ct][4 * g], Bt.acc[ct][4 * g + 1],
                                    Bt.acc[ct][4 * g + 2], Bt.acc[ct][4 * g + 3]);
        }
        __syncthreads();
        const int qb = which ? (pp << 5) : ((127 - pp) << 5);
        #pragma unroll
        for (int i = 0; i < 4; ++i) {
            const int e = tid + i * 512;
            const int q = e >> 6, d = e & 63;
            float ms = mbuf[0][q];
            #pragma unroll
            for (int wv = 1; wv < 8; ++wv) ms = fmaxf(ms, mbuf[wv][q]);
            float ls = 0.f, os = 0.f;
            #pragma unroll
            for (int wv = 0; wv < 8; ++wv) {
                const float e_ = exp2f(mbuf[wv][q] - ms);
                ls += lbuf[wv][q] * e_;
                os += accbuf[wv][q][d] * e_;
            }
            out[((long)b * T_ + qb + q) * 64 + d] = os / ls;
        }
        __syncthreads();
    }
}

extern "C" void kernel_launch(void* const* d_in, const int* in_sizes, int n_in,
                              void* d_out, int out_size, void* d_ws, size_t ws_size,
                              hipStream_t stream)
{
    const float* emb = (const float*)d_in[0];
    const float* Wq  = (const float*)d_in[1];
    const float* Wk  = (const float*)d_in[2];
    const float* Wv  = (const float*)d_in[3];
    float* out = (float*)d_out;

    unsigned short* Qp = (unsigned short*)d_ws;
    unsigned short* Kp = Qp + (size_t)B_ * T_ * A_;
    unsigned short* Vp = Kp + (size_t)B_ * T_ * A_;
    unsigned short* Wp = Vp + (size_t)B_ * T_ * A_;

    prep_w<<<dim3(48), dim3(256), 0, stream>>>(Wq, Wk, Wv, Wp);
    qkv_proj_kernel<<<dim3(512), dim3(768), 0, stream>>>(emb, Wp, Qp, Kp, Vp);
    attn_kernel<<<dim3(256), dim3(512), 0, stream>>>(Qp, Kp, Vp, out);
}